// Round 1
// baseline (503.397 us; speedup 1.0000x reference)
//
#include <hip/hip_runtime.h>
#include <stdint.h>

// ---------------- problem constants ----------------
constexpr int Bn = 64;
constexpr int Nn = 8;
constexpr int Vn = 128000;
constexpr int CH = 32;            // chunks per row
constexpr int CHUNK = Vn / CH;    // 4000 floats
constexpr int F4 = CHUNK / 4;     // 1000 float4 per chunk
constexpr float EPSf = 1e-20f;
constexpr float TINYf = 1.17549435082228751e-38f;  // FLT_MIN, np.finfo(f32).tiny

// ---------------- Threefry-2x32 (JAX-exact) ----------------
struct TFOut { uint32_t a, b; };

__host__ __device__ constexpr TFOut tf2x32(uint32_t k0, uint32_t k1,
                                           uint32_t x0, uint32_t x1) {
  uint32_t k2 = k0 ^ k1 ^ 0x1BD11BDAu;
  x0 += k0; x1 += k1;
#define TFR(r) { x0 += x1; x1 = (uint32_t)((x1 << (r)) | (x1 >> (32 - (r)))); x1 ^= x0; }
  TFR(13) TFR(15) TFR(26) TFR(6)
  x0 += k1; x1 += k2 + 1u;
  TFR(17) TFR(29) TFR(16) TFR(24)
  x0 += k2; x1 += k0 + 2u;
  TFR(13) TFR(15) TFR(26) TFR(6)
  x0 += k0; x1 += k1 + 3u;
  TFR(17) TFR(29) TFR(16) TFR(24)
  x0 += k1; x1 += k2 + 4u;
  TFR(13) TFR(15) TFR(26) TFR(6)
  x0 += k2; x1 += k0 + 5u;
#undef TFR
  return TFOut{x0, x1};
}

// jax.random.key(1) -> key data (0,1); partitionable split -> fold-like.
constexpr TFOut KU  = tf2x32(0u, 1u, 0u, 0u);  // ku = split[0]
constexpr TFOut KR  = tf2x32(0u, 1u, 0u, 1u);  // kr = split[1]
constexpr TFOut KB_ = tf2x32(0u, 1u, 0u, 2u);  // kb = split[2]

// ---------------- device helpers ----------------
__device__ __forceinline__ float jax_u01(uint32_t bits) {
  return __uint_as_float((bits >> 9) | 0x3f800000u) - 1.0f;
}

__device__ __forceinline__ uint32_t rbits(uint32_t k0, uint32_t k1, uint32_t t) {
  TFOut o = tf2x32(k0, k1, 0u, t);
  return o.a ^ o.b;
}

__device__ __forceinline__ float gumbel_at(uint32_t k0, uint32_t k1, uint32_t t) {
  float u = jax_u01(rbits(k0, k1, t));
  float uu = fmaxf(TINYf, u + TINYf);
  return -logf(-logf(uu));
}

// order-preserving float->uint map, packed with ~v so max() == JAX first-index argmax
__device__ __forceinline__ unsigned long long packsc(float s, uint32_t v) {
  uint32_t u = __float_as_uint(s);
  uint32_t m = (u & 0x80000000u) ? ~u : (u | 0x80000000u);
  return ((unsigned long long)m << 32) | (unsigned long long)(~v);
}

// accept bit for flat draft position j
__device__ __forceinline__ int accept_bit(int j, const int* __restrict__ ids,
                                          const float* __restrict__ draft,
                                          const float* __restrict__ verify) {
  int b = j >> 3, n = j & 7;
  float u = jax_u01(rbits(KU.a, KU.b, (uint32_t)j));
  int tok = ids[j];
  float p = verify[(size_t)(b * (Nn + 1) + n) * Vn + tok];
  float q = draft[(size_t)(b * Nn + n) * Vn + tok];
  return (u * q < p) ? 1 : 0;
}

// ---------------- kernel A: accept/emitted + prefix outputs + residual partials ----------------
__global__ void __launch_bounds__(256)
KA(const int* __restrict__ ids, const float* __restrict__ draft,
   const float* __restrict__ verify, int* __restrict__ out,
   float* __restrict__ partial, unsigned long long* __restrict__ R,
   int* __restrict__ em_g, int* __restrict__ done) {
  int blk = blockIdx.x;
  int b = blk >> 5, c = blk & 31;
  __shared__ int s_acc[8];
  __shared__ float sred[256];
  if (threadIdx.x < 8) s_acc[threadIdx.x] = accept_bit(b * 8 + threadIdx.x, ids, draft, verify);
  __syncthreads();
  int em = 0;
  while (em < 8 && s_acc[em]) em++;

  if (c == 0) {
    if (threadIdx.x < Nn + 1)
      out[b * (Nn + 1) + threadIdx.x] =
          (threadIdx.x < em) ? ids[b * Nn + threadIdx.x] : -1;  // slot em fixed by KB's last block
    if (threadIdx.x == 0) {
      int acc = s_acc[0] + s_acc[1] + s_acc[2] + s_acc[3] + s_acc[4] + s_acc[5] + s_acc[6] + s_acc[7];
      out[Bn * (Nn + 1) + b] = acc;        // accepted_token_num
      out[Bn * (Nn + 1) + Bn + b] = em;    // emitted_token_num
      em_g[b] = em;                        // published for KB (no recompute there)
      R[b] = 0ull;
      done[b] = 0;
    }
  }
  if (em >= Nn) return;  // wave-uniform per block

  const float4* t4 = (const float4*)(verify + (size_t)(b * (Nn + 1) + em) * Vn + c * CHUNK);
  const float4* d4 = (const float4*)(draft + (size_t)(b * Nn + em) * Vn + c * CHUNK);
  float s = 0.0f;
  for (int i = threadIdx.x; i < F4; i += 256) {
    float4 t = t4[i], d = d4[i];
    s += fmaxf(t.x - d.x, 0.0f);
    s += fmaxf(t.y - d.y, 0.0f);
    s += fmaxf(t.z - d.z, 0.0f);
    s += fmaxf(t.w - d.w, 0.0f);
  }
  sred[threadIdx.x] = s;
  __syncthreads();
  for (int st = 128; st > 0; st >>= 1) {
    if (threadIdx.x < st) sred[threadIdx.x] += sred[threadIdx.x + st];
    __syncthreads();
  }
  if (threadIdx.x == 0) partial[blk] = sred[0];
}

// ---------------- kernel B: gumbel-argmax + final-token write (last block per row) ----------------
__global__ void __launch_bounds__(256)
KB(const int* __restrict__ ids, const float* __restrict__ draft,
   const float* __restrict__ verify, const float* __restrict__ partial,
   unsigned long long* __restrict__ R, const int* __restrict__ em_g,
   int* __restrict__ done, int* __restrict__ out) {
  int blk = blockIdx.x;
  int b = blk >> 5, c = blk & 31;
  __shared__ unsigned long long smax[256];
  int em = em_g[b];

  float best = -__builtin_inff();
  uint32_t bestv = 0u;

  if (em < Nn) {
    // S: parallel loads, then in-register accumulation in EXACT baseline order 0..31
    // (bit-identical to the previous serial loop; avoids the 32-deep dependent-load chain).
    float pv = partial[b * CH + (threadIdx.x & 31)];
    float S = 0.0f;
#pragma unroll
    for (int i = 0; i < CH; i++) S += __shfl(pv, i, 64);
    float Sm = fmaxf(S, EPSf);

    const float4* t4 = (const float4*)(verify + (size_t)(b * (Nn + 1) + em) * Vn + c * CHUNK);
    const float4* d4 = (const float4*)(draft + (size_t)(b * Nn + em) * Vn + c * CHUNK);
    uint32_t trow = (uint32_t)(b * Nn + em) * (uint32_t)Vn;
    for (int i = threadIdx.x; i < F4; i += 256) {
      float4 t = t4[i], d = d4[i];
      uint32_t v0 = (uint32_t)(c * CHUNK + i * 4);
      float tv[4] = {t.x, t.y, t.z, t.w};
      float dv[4] = {d.x, d.y, d.z, d.w};
#pragma unroll
      for (int k = 0; k < 4; k++) {
        float r = fmaxf(tv[k] - dv[k], 0.0f);
        float logit = logf(r / Sm + EPSf);
        float sc = gumbel_at(KR.a, KR.b, trow + v0 + k) + logit;
        if (sc > best) { best = sc; bestv = v0 + k; }  // ascending v => first occurrence
      }
    }
  } else {
    // bonus: argmax over gumbel(kb) + log(verify[b,N,:] + EPS)
    const float4* p4 = (const float4*)(verify + (size_t)(b * (Nn + 1) + Nn) * Vn + c * CHUNK);
    uint32_t trow = (uint32_t)b * (uint32_t)Vn;
    for (int i = threadIdx.x; i < F4; i += 256) {
      float4 p = p4[i];
      uint32_t v0 = (uint32_t)(c * CHUNK + i * 4);
      float pvv[4] = {p.x, p.y, p.z, p.w};
#pragma unroll
      for (int k = 0; k < 4; k++) {
        float logit = logf(pvv[k] + EPSf);
        float sc = gumbel_at(KB_.a, KB_.b, trow + v0 + k) + logit;
        if (sc > best) { best = sc; bestv = v0 + k; }
      }
    }
  }

  smax[threadIdx.x] = packsc(best, bestv);
  __syncthreads();
  for (int st = 128; st > 0; st >>= 1) {
    if (threadIdx.x < st) {
      unsigned long long o = smax[threadIdx.x + st];
      if (o > smax[threadIdx.x]) smax[threadIdx.x] = o;
    }
    __syncthreads();
  }
  if (threadIdx.x == 0) {
    atomicMax(&R[b], smax[0]);            // device-scope, commutative -> order-independent
    __threadfence();                      // release our max before signaling
    if (atomicAdd(&done[b], 1) == CH - 1) {
      // last block of this row: all 31 other maxes are globally visible (their fence
      // ordered atomicMax before the counter add). Read via atomic for device-scope load.
      unsigned long long rv = atomicAdd(&R[b], 0ull);
      out[b * (Nn + 1) + em] = (int)(~(uint32_t)(rv & 0xFFFFFFFFull));
    }
  }
}

// ---------------- launch ----------------
extern "C" void kernel_launch(void* const* d_in, const int* in_sizes, int n_in,
                              void* d_out, int out_size, void* d_ws, size_t ws_size,
                              hipStream_t stream) {
  const int* ids = (const int*)d_in[0];
  const float* draft = (const float*)d_in[1];
  const float* verify = (const float*)d_in[2];
  int* out = (int*)d_out;

  char* w = (char*)d_ws;
  float* partial = (float*)w;                                  // 2048 floats = 8192 B
  unsigned long long* R = (unsigned long long*)(w + 8192);     // 64 * 8 B = 512 B
  int* em_g = (int*)(w + 8704);                                // 64 * 4 B
  int* done = (int*)(w + 8960);                                // 64 * 4 B

  KA<<<dim3(Bn * CH), dim3(256), 0, stream>>>(ids, draft, verify, out, partial, R, em_g, done);
  KB<<<dim3(Bn * CH), dim3(256), 0, stream>>>(ids, draft, verify, partial, R, em_g, done, out);
}